// Round 4
// baseline (513.791 us; speedup 1.0000x reference)
//
#include <hip/hip_runtime.h>
#include <hip/hip_cooperative_groups.h>

#define B_   256
#define L_   1024
#define H_   256   // DEC_H == ENC_D
#define EMB_ 128
#define OUT_ 172

typedef float f32x4 __attribute__((ext_vector_type(4)));
typedef __bf16 bf16x8 __attribute__((ext_vector_type(8)));
typedef unsigned short us8 __attribute__((ext_vector_type(8)));

static __device__ __forceinline__ unsigned short f2bf(float f) {
    unsigned u = __float_as_uint(f);
    u += 0x7fffu + ((u >> 16) & 1u);   // RNE
    return (unsigned short)(u >> 16);
}
static __device__ __forceinline__ us8 cvt8(const float* __restrict__ p) {
    float4 x0 = *(const float4*)p, x1 = *(const float4*)(p + 4);
    us8 v;
    v[0]=f2bf(x0.x); v[1]=f2bf(x0.y); v[2]=f2bf(x0.z); v[3]=f2bf(x0.w);
    v[4]=f2bf(x1.x); v[5]=f2bf(x1.y); v[6]=f2bf(x1.z); v[7]=f2bf(x1.w);
    return v;
}
static __device__ __forceinline__ us8 cvt8r(float4 x0, float4 x1) {
    us8 v;
    v[0]=f2bf(x0.x); v[1]=f2bf(x0.y); v[2]=f2bf(x0.z); v[3]=f2bf(x0.w);
    v[4]=f2bf(x1.x); v[5]=f2bf(x1.y); v[6]=f2bf(x1.z); v[7]=f2bf(x1.w);
    return v;
}
static __device__ __forceinline__ float tanh_fast(float x) {
    float e = __expf(2.f * x);
    return 1.f - 2.f * __builtin_amdgcn_rcpf(e + 1.f);
}
static __device__ __forceinline__ float sigm_fast(float x) {
    return __builtin_amdgcn_rcpf(1.f + __expf(-x));
}

#define TS 40       // LDS row stride for 64x32 bf16 GEMM tiles
#define ROWSTR 264  // 256 bf16 + 8 pad

// ================================================= K1: cooperative mega-kernel
// grid 256 (block = batch row), block 512 threads, 1 block/CU guaranteed.
// phase 1: blocks 0..63 do gates GEMM; all blocks prefetch enc tiles 0,1 to regs
// grid.sync()
// phase 2: every block computes OWN row's LSTM + hW2 GEMV (LDS-staged W2)
// phase 3: fused attention (as R3), ctx written normalized bf16 to A3u[b][256:512]
__global__ __launch_bounds__(512, 2) void k_fused(
    const float* __restrict__ h0, const float* __restrict__ c0,
    const float* __restrict__ o_t, const float* __restrict__ enc,
    const int* __restrict__ lt, const float* __restrict__ emb,
    const float* __restrict__ W_ih, const float* __restrict__ W_hh,
    const float* __restrict__ b_ih, const float* __restrict__ b_hh,
    const float* __restrict__ W1, const float* __restrict__ W2,
    const float* __restrict__ beta, float* __restrict__ gates,
    unsigned short* __restrict__ A3u, float* __restrict__ out)
{
    const int blk = blockIdx.x;      // == batch row b
    const int tid = threadIdx.x;
    const int wave = tid >> 6, lane = tid & 63;
    const int quad = lane >> 4, l15 = lane & 15;

    __shared__ __align__(16) union {
        struct { unsigned short As[64 * TS]; unsigned short Bs[64 * TS]; } g;
        unsigned short encs[3][16 * ROWSTR];
        float W2c[256 * 33];
    } su;
    __shared__ float h_s[256];
    __shared__ float hw2p[512];
    __shared__ float hw2_s[256];
    __shared__ float sp[2][8][16];
    __shared__ float wexp[2][16];
    __shared__ float2 cr[512];
    __shared__ float ssum_s;

    // ---------------- phase 1: gates GEMM (blocks 0..63)
    if (blk < 64) {
        const int m0 = (blk >> 4) * 64, n0 = (blk & 15) * 64;
        const int mh = (wave & 1) * 32, nq = (wave >> 1) * 16;
        f32x4 acc[2] = {{0,0,0,0},{0,0,0,0}};
        const int st = tid & 255, sm = st >> 2, sk8 = (st & 3) * 8;
        int ltv = 0;
        if (tid < 256) ltv = lt[m0 + sm];
        for (int kc = 0; kc < 20; kc++) {
            const int k = kc * 32 + sk8;
            if (tid < 256) {
                const float* ap;
                if (k < 128)      ap = emb + ltv * EMB_ + k;
                else if (k < 384) ap = o_t + (m0 + sm) * H_ + (k - 128);
                else              ap = h0  + (m0 + sm) * H_ + (k - 384);
                *(us8*)&su.g.As[sm * TS + sk8] = cvt8(ap);
            } else {
                const int j = n0 + sm;
                const float* bp = (k < 384) ? (W_ih + j * 384 + k)
                                            : (W_hh + j * 256 + (k - 384));
                *(us8*)&su.g.Bs[sm * TS + sk8] = cvt8(bp);
            }
            __syncthreads();
            bf16x8 bfr = __builtin_bit_cast(bf16x8, *(const us8*)&su.g.Bs[(nq + l15) * TS + quad * 8]);
            #pragma unroll
            for (int mf = 0; mf < 2; mf++) {
                bf16x8 a = __builtin_bit_cast(bf16x8, *(const us8*)&su.g.As[(mh + mf * 16 + l15) * TS + quad * 8]);
                acc[mf] = __builtin_amdgcn_mfma_f32_16x16x32_bf16(a, bfr, acc[mf], 0, 0, 0);
            }
            __syncthreads();
        }
        const int n = n0 + nq + l15;
        const float bias = b_ih[n] + b_hh[n];
        #pragma unroll
        for (int mf = 0; mf < 2; mf++)
            #pragma unroll
            for (int r = 0; r < 4; r++)
                gates[(m0 + mh + mf * 16 + quad * 4 + r) * 1024 + n] = acc[mf][r] + bias;
    }

    // ---------------- prefetch enc tiles 0,1 into regs (all blocks)
    const float* encb = enc + (size_t)blk * L_ * H_;
    const int srow = tid >> 5, scol = (tid & 31) * 8;
    float4 x0, x1, y0, y1;
    { const float* p = encb + srow * 256 + scol;        x0 = *(const float4*)p; x1 = *(const float4*)(p + 4); }
    { const float* p = encb + 4096 + srow * 256 + scol; y0 = *(const float4*)p; y1 = *(const float4*)(p + 4); }

    cooperative_groups::this_grid().sync();

    // ---------------- phase 2: LSTM + hW2 for own row b = blk
    const int b = blk;
    if (tid < 256) {
        const float* g = gates + b * 1024;
        float gi = g[tid], gf = g[256 + tid], gg = g[512 + tid], go = g[768 + tid];
        float c = sigm_fast(gf) * c0[b * H_ + tid] + sigm_fast(gi) * tanh_fast(gg);
        float h = sigm_fast(go) * tanh_fast(c);
        out[b * H_ + tid]           = h;   // h_t
        out[B_ * H_ + b * H_ + tid] = c;   // c_t
        A3u[b * 512 + tid] = f2bf(h);      // bf16 h for downstream GEMMs
        h_s[tid] = h;
    }
    // hW2[b][t] = sum_k h[k] * W2[t][k]; LDS-staged W2, split k over thread pairs
    float hacc = 0.f;
    const int t2 = tid & 255, jb = (tid >> 8) * 16;
    for (int kc = 0; kc < 8; kc++) {
        __syncthreads();   // h_s ready / previous chunk consumed
        {   // stage W2 chunk [256 rows][32 k] -> W2c[r][33]
            const int rr = tid >> 1, cb = (tid & 1) * 16;
            const float* wp = W2 + rr * 256 + kc * 32 + cb;
            float4 w0 = *(const float4*)wp, w1 = *(const float4*)(wp + 4);
            float4 w2v = *(const float4*)(wp + 8), w3v = *(const float4*)(wp + 12);
            float* d = &su.W2c[rr * 33 + cb];
            d[0]=w0.x; d[1]=w0.y; d[2]=w0.z; d[3]=w0.w;
            d[4]=w1.x; d[5]=w1.y; d[6]=w1.z; d[7]=w1.w;
            d[8]=w2v.x; d[9]=w2v.y; d[10]=w2v.z; d[11]=w2v.w;
            d[12]=w3v.x; d[13]=w3v.y; d[14]=w3v.z; d[15]=w3v.w;
        }
        __syncthreads();
        #pragma unroll
        for (int j = 0; j < 16; j++)
            hacc += h_s[kc * 32 + jb + j] * su.W2c[t2 * 33 + jb + j];
    }
    hw2p[tid] = hacc;
    __syncthreads();       // also guards last W2c reads before encs reuse
    if (tid < 256) hw2_s[tid] = hw2p[tid] + hw2p[tid + 256];
    // store tile 0 into buf 0 (W2c dead), rotate prefetch regs
    *(us8*)&su.encs[0][srow * ROWSTR + scol] = cvt8r(x0, x1);
    x0 = y0; x1 = y1;
    __syncthreads();       // hw2_s + tile0 visible

    // ---------------- phase 3: fused attention
    bf16x8 wf[8][2];
    float hw2v[2], betav[2];
    #pragma unroll
    for (int nt = 0; nt < 2; nt++) {
        int n = wave * 32 + nt * 16 + l15;
        hw2v[nt]  = hw2_s[n];
        betav[nt] = beta[n];
        #pragma unroll
        for (int ks = 0; ks < 8; ks++)
            wf[ks][nt] = __builtin_bit_cast(bf16x8, cvt8(W1 + n * 256 + ks * 32 + quad * 8));
    }

    const int cp = tid & 127, q = tid >> 7;
    float2 ctx2 = {0.f, 0.f};
    float ssum = 0.f;

    for (int it = 0; it < 64; it++) {
        const int cur = it % 3;
        const int nxt = (it + 1) % 3;
        const int par = it & 1;
        float4 yy0 = {0,0,0,0}, yy1 = {0,0,0,0};
        if (it < 62) {
            const float* p = encb + (it + 2) * 4096 + srow * 256 + scol;
            yy0 = *(const float4*)p; yy1 = *(const float4*)(p + 4);
        }
        f32x4 acc0 = {0,0,0,0}, acc1 = {0,0,0,0};
        const unsigned short* arow = &su.encs[cur][l15 * ROWSTR + quad * 8];
        #pragma unroll
        for (int ks = 0; ks < 8; ks++) {
            bf16x8 a = __builtin_bit_cast(bf16x8, *(const us8*)(arow + ks * 32));
            acc0 = __builtin_amdgcn_mfma_f32_16x16x32_bf16(a, wf[ks][0], acc0, 0, 0, 0);
            acc1 = __builtin_amdgcn_mfma_f32_16x16x32_bf16(a, wf[ks][1], acc1, 0, 0, 0);
        }
        if (it < 63)
            *(us8*)&su.encs[nxt][srow * ROWSTR + scol] = cvt8r(x0, x1);
        float p4[4];
        #pragma unroll
        for (int r = 0; r < 4; r++) {
            float t0 = tanh_fast(acc0[r] + hw2v[0]);
            float t1 = tanh_fast(acc1[r] + hw2v[1]);
            p4[r] = betav[0] * t0 + betav[1] * t1;
        }
        #pragma unroll
        for (int m = 1; m < 16; m <<= 1) {
            p4[0] += __shfl_xor(p4[0], m);
            p4[1] += __shfl_xor(p4[1], m);
            p4[2] += __shfl_xor(p4[2], m);
            p4[3] += __shfl_xor(p4[3], m);
        }
        if (l15 == 0) {
            #pragma unroll
            for (int r = 0; r < 4; r++) sp[par][wave][quad * 4 + r] = p4[r];
        }
        __syncthreads();               // A: sp + buf nxt visible
        if (tid < 16) {
            float sc = sp[par][0][tid] + sp[par][1][tid] + sp[par][2][tid] + sp[par][3][tid]
                     + sp[par][4][tid] + sp[par][5][tid] + sp[par][6][tid] + sp[par][7][tid];
            wexp[par][tid] = __expf(sc);
        }
        __syncthreads();               // B: wexp visible
        {
            const unsigned* base = (const unsigned*)&su.encs[cur][0];
            float cx = ctx2.x, cy = ctx2.y;
            #pragma unroll
            for (int r = 0; r < 4; r++) {
                const int row = q * 4 + r;
                unsigned u = base[row * (ROWSTR / 2) + cp];
                float wv = wexp[par][row];
                cx += wv * __uint_as_float(u << 16);
                cy += wv * __uint_as_float(u & 0xffff0000u);
            }
            ctx2.x = cx; ctx2.y = cy;
        }
        if (tid == 0) {
            float s2 = 0.f;
            #pragma unroll
            for (int r = 0; r < 16; r++) s2 += wexp[par][r];
            ssum += s2;
        }
        x0 = yy0; x1 = yy1;
        __syncthreads();               // C: buffer safe to overwrite
    }
    if (tid == 0) ssum_s = ssum;
    cr[tid] = ctx2;
    __syncthreads();
    if (tid < 128) {
        float2 a0 = cr[tid], a1 = cr[tid + 128], a2 = cr[tid + 256], a3 = cr[tid + 384];
        float inv = __builtin_amdgcn_rcpf(ssum_s);
        float cx = (a0.x + a1.x + a2.x + a3.x) * inv;
        float cy = (a0.y + a1.y + a2.y + a3.y) * inv;
        unsigned pack = (unsigned)f2bf(cx) | ((unsigned)f2bf(cy) << 16);
        ((unsigned*)A3u)[b * 256 + 128 + tid] = pack;   // ctx cols 256+2t, 256+2t+1
    }
}

// ================================================= K2: o_new = tanh([h|ctx] @ W3^T), grid 16
__global__ __launch_bounds__(256) void k_out3(
    const unsigned short* __restrict__ A3u, const float* __restrict__ W3,
    float* __restrict__ out, unsigned short* __restrict__ A4u)
{
    const int m0 = (blockIdx.x >> 2) * 64;
    const int n0 = (blockIdx.x & 3) * 64;
    const int tid = threadIdx.x;
    const int w = tid >> 6, lane = tid & 63, quad = lane >> 4, l15 = lane & 15;
    __shared__ __align__(16) unsigned short As[64 * TS];
    __shared__ __align__(16) unsigned short Bs[64 * TS];
    f32x4 acc[4] = {{0,0,0,0},{0,0,0,0},{0,0,0,0},{0,0,0,0}};
    const int sm = tid >> 2, sk8 = (tid & 3) * 8;
    for (int kc = 0; kc < 16; kc++) {
        const int k = kc * 32 + sk8;
        *(us8*)&As[sm * TS + sk8] = *(const us8*)&A3u[(m0 + sm) * 512 + k];
        *(us8*)&Bs[sm * TS + sk8] = cvt8(W3 + (n0 + sm) * 512 + k);
        __syncthreads();
        bf16x8 a = __builtin_bit_cast(bf16x8, *(const us8*)&As[(w * 16 + l15) * TS + quad * 8]);
        #pragma unroll
        for (int nt = 0; nt < 4; nt++) {
            bf16x8 bfr = __builtin_bit_cast(bf16x8, *(const us8*)&Bs[(nt * 16 + l15) * TS + quad * 8]);
            acc[nt] = __builtin_amdgcn_mfma_f32_16x16x32_bf16(a, bfr, acc[nt], 0, 0, 0);
        }
        __syncthreads();
    }
    #pragma unroll
    for (int nt = 0; nt < 4; nt++)
        #pragma unroll
        for (int r = 0; r < 4; r++) {
            int row = m0 + w * 16 + quad * 4 + r, col = n0 + nt * 16 + l15;
            float o = tanh_fast(acc[nt][r]);
            out[2 * B_ * H_ + row * 256 + col] = o;   // o_new
            A4u[row * 256 + col] = f2bf(o);
        }
}

// ================================================= K3: logit = softmax(o_new @ W_out^T), grid 4
__global__ __launch_bounds__(256) void k_logit(
    const unsigned short* __restrict__ A4u, const float* __restrict__ W_out,
    float* __restrict__ out)
{
    const int m0 = blockIdx.x * 64;
    const int tid = threadIdx.x;
    const int w = tid >> 6, lane = tid & 63, quad = lane >> 4, l15 = lane & 15;
    __shared__ __align__(16) unsigned short As[64 * TS];
    __shared__ __align__(16) unsigned short Bs[192 * TS];
    __shared__ float lg[64][196];
    f32x4 acc[12];
    #pragma unroll
    for (int nt = 0; nt < 12; nt++) acc[nt] = (f32x4){0,0,0,0};
    const int sm = tid >> 2, sk8 = (tid & 3) * 8;
    for (int kc = 0; kc < 8; kc++) {
        const int k = kc * 32 + sk8;
        *(us8*)&As[sm * TS + sk8] = *(const us8*)&A4u[(m0 + sm) * 256 + k];
        #pragma unroll
        for (int rr = 0; rr < 3; rr++) {
            int j = rr * 64 + sm;
            us8 v = {0,0,0,0,0,0,0,0};
            if (j < OUT_) v = cvt8(W_out + j * 256 + k);
            *(us8*)&Bs[j * TS + sk8] = v;
        }
        __syncthreads();
        bf16x8 a = __builtin_bit_cast(bf16x8, *(const us8*)&As[(w * 16 + l15) * TS + quad * 8]);
        #pragma unroll
        for (int nt = 0; nt < 12; nt++) {
            bf16x8 bfr = __builtin_bit_cast(bf16x8, *(const us8*)&Bs[(nt * 16 + l15) * TS + quad * 8]);
            acc[nt] = __builtin_amdgcn_mfma_f32_16x16x32_bf16(a, bfr, acc[nt], 0, 0, 0);
        }
        __syncthreads();
    }
    #pragma unroll
    for (int nt = 0; nt < 12; nt++)
        #pragma unroll
        for (int r = 0; r < 4; r++)
            lg[w * 16 + quad * 4 + r][nt * 16 + l15] = acc[nt][r];
    __syncthreads();
    const int m = tid >> 2, p = tid & 3;
    const int cb = p * 43;
    float mx = -1e30f;
    for (int c = 0; c < 43; c++) mx = fmaxf(mx, lg[m][cb + c]);
    mx = fmaxf(mx, __shfl_xor(mx, 1));
    mx = fmaxf(mx, __shfl_xor(mx, 2));
    float s = 0.f;
    for (int c = 0; c < 43; c++) { float e = __expf(lg[m][cb + c] - mx); lg[m][cb + c] = e; s += e; }
    s += __shfl_xor(s, 1);
    s += __shfl_xor(s, 2);
    float inv = 1.f / s;
    for (int c = 0; c < 43; c++)
        out[3 * B_ * H_ + (m0 + m) * OUT_ + cb + c] = lg[m][cb + c] * inv;
}

// ================================================= host
extern "C" void kernel_launch(void* const* d_in, const int* in_sizes, int n_in,
                              void* d_out, int out_size, void* d_ws, size_t ws_size,
                              hipStream_t stream)
{
    const float* h0   = (const float*)d_in[0];
    const float* c0   = (const float*)d_in[1];
    const float* o_t  = (const float*)d_in[2];
    const float* enc  = (const float*)d_in[3];
    const int*   lt   = (const int*)  d_in[4];
    const float* emb  = (const float*)d_in[5];
    const float* W_ih = (const float*)d_in[6];
    const float* W_hh = (const float*)d_in[7];
    const float* b_ih = (const float*)d_in[8];
    const float* b_hh = (const float*)d_in[9];
    const float* W1   = (const float*)d_in[10];
    const float* W2   = (const float*)d_in[11];
    const float* W3   = (const float*)d_in[12];
    const float* Wo   = (const float*)d_in[13];
    const float* beta = (const float*)d_in[14];
    float* out = (float*)d_out;
    float* ws  = (float*)d_ws;

    float*          gates = ws;                                         // 256*1024 f32
    unsigned short* A3u   = (unsigned short*)(ws + 262144);             // 256*512 bf16 [h|ctx]
    unsigned short* A4u   = (unsigned short*)(ws + 262144 + 65536);     // 256*256 bf16 o_new

    void* args[] = { (void*)&h0, (void*)&c0, (void*)&o_t, (void*)&enc, (void*)&lt,
                     (void*)&emb, (void*)&W_ih, (void*)&W_hh, (void*)&b_ih, (void*)&b_hh,
                     (void*)&W1, (void*)&W2, (void*)&beta,
                     (void*)&gates, (void*)&A3u, (void*)&out };
    hipLaunchCooperativeKernel((const void*)k_fused, dim3(256), dim3(512), args, 0, stream);

    k_out3 <<<16, 256, 0, stream>>>(A3u, W3, out, A4u);
    k_logit<<<4, 256, 0, stream>>>(A4u, Wo, out);
}